// Round 17
// baseline (350.275 us; speedup 1.0000x reference)
//
#include <hip/hip_runtime.h>
#include <math.h>

#define TPB 256
#define NEG_SLOPE 0.2f
#define EPB 2048          // edges per block-chunk in streaming CSR kernels
#define BK 512            // nodes per bucket (dst>>9)

static inline int cdiv_l(long a, int b){ return (int)((a + b - 1) / b); }

typedef float v2f __attribute__((ext_vector_type(2)));

__device__ __forceinline__ ushort f2bf(float f){
  unsigned u = __float_as_uint(f);
  unsigned r = u + 0x7fffu + ((u >> 16) & 1u);   // RNE
  return (ushort)(r >> 16);
}
__device__ __forceinline__ float bf2f(unsigned hi16){ return __uint_as_float(hi16 << 16); }
__device__ __forceinline__ unsigned pbf2(float a, float b){
  return (unsigned)f2bf(a) | ((unsigned)f2bf(b) << 16);
}

// ---------------- GEMM (4 nodes x 4 ch per thread) + attention dots + fp8 payload ----
template<int Fin, int HC, int C, typename XT>
__global__ __launch_bounds__(256) void gemm2_k(const XT* __restrict__ X,
        const float* __restrict__ W, const float* __restrict__ as_,
        const float* __restrict__ ad_, float* __restrict__ es, float* __restrict__ ed,
        unsigned char* __restrict__ Hb, int N){
  constexpr int TPN = HC / 4;         // threads per node (column groups)
  constexpr int NPB = (256 / TPN) * 4;// nodes per block
  constexpr int H   = HC / C;
  constexpr int RG  = C / 4;          // lanes per (node, head)
  __shared__ float Wl[Fin * HC];
  for (int i = threadIdx.x; i < Fin * HC; i += 256) Wl[i] = W[i];
  __syncthreads();
  const int t  = threadIdx.x;
  const int cg = t % TPN;             // column group
  const int ng = t / TPN;             // node quad
  const int jt = cg * 4;
  const int nb = blockIdx.x * NPB + ng * 4;
  const XT* xr[4];
#pragma unroll
  for (int m = 0; m < 4; ++m)
    xr[m] = X + (size_t)((nb + m < N) ? nb + m : 0) * Fin;

  float acc[4][4];
#pragma unroll
  for (int m = 0; m < 4; ++m)
#pragma unroll
    for (int j = 0; j < 4; ++j) acc[m][j] = 0.f;

  for (int k = 0; k < Fin; k += 4){
    float xv[4][4];
#pragma unroll
    for (int m = 0; m < 4; ++m){
      if constexpr (sizeof(XT) == 4){
        float4 v = *(const float4*)(xr[m] + k);
        xv[m][0] = v.x; xv[m][1] = v.y; xv[m][2] = v.z; xv[m][3] = v.w;
      } else {
        uint2 u = *(const uint2*)(xr[m] + k);
        xv[m][0] = bf2f(u.x & 0xffffu); xv[m][1] = bf2f(u.x >> 16);
        xv[m][2] = bf2f(u.y & 0xffffu); xv[m][3] = bf2f(u.y >> 16);
      }
    }
#pragma unroll
    for (int kk = 0; kk < 4; ++kk){
      float w0 = Wl[(k + kk) * HC + jt + 0];
      float w1 = Wl[(k + kk) * HC + jt + 1];
      float w2 = Wl[(k + kk) * HC + jt + 2];
      float w3 = Wl[(k + kk) * HC + jt + 3];
#pragma unroll
      for (int m = 0; m < 4; ++m){
        acc[m][0] = fmaf(xv[m][kk], w0, acc[m][0]);
        acc[m][1] = fmaf(xv[m][kk], w1, acc[m][1]);
        acc[m][2] = fmaf(xv[m][kk], w2, acc[m][2]);
        acc[m][3] = fmaf(xv[m][kk], w3, acc[m][3]);
      }
    }
  }

  const int head = jt / C;
  const float* asp = as_ + head * C + (jt % C);
  const float* adp = ad_ + head * C + (jt % C);
#pragma unroll
  for (int m = 0; m < 4; ++m){
    int n = nb + m;
    bool v = (n < N);
    if (v){
      int pk8 = __builtin_amdgcn_cvt_pk_fp8_f32(acc[m][0], acc[m][1], 0, false);
      pk8     = __builtin_amdgcn_cvt_pk_fp8_f32(acc[m][2], acc[m][3], pk8, true);
      *(int*)(Hb + (size_t)n * HC + jt) = pk8;
    }
    float ps = 0.f, pd = 0.f;
#pragma unroll
    for (int j = 0; j < 4; ++j){
      ps = fmaf(acc[m][j], asp[j], ps);
      pd = fmaf(acc[m][j], adp[j], pd);
    }
#pragma unroll
    for (int off = RG >> 1; off >= 1; off >>= 1){
      ps += __shfl_xor(ps, off);
      pd += __shfl_xor(pd, off);
    }
    if (v && (cg % RG) == 0){
      es[n * H + head] = ps;
      ed[n * H + head] = pd;
    }
  }
}

// ---------------- CSR build: bucket partition + per-bucket counting sort ----------------

__global__ __launch_bounds__(256) void bucket_hist_k(const int* __restrict__ dst,
                        int* __restrict__ bcount, int E){
  __shared__ int lh[128];
  const int t = threadIdx.x;
  for (int i = t; i < 128; i += TPB) lh[i] = 0;
  __syncthreads();
  const int c0 = blockIdx.x * EPB;
  int i1 = c0 + EPB; if (i1 > E) i1 = E;
  for (int i = c0 + t; i < i1; i += TPB)
    atomicAdd(&lh[dst[i] >> 9], 1);
  __syncthreads();
  for (int i = t; i < 128; i += TPB)
    if (lh[i]) atomicAdd(&bcount[i], lh[i]);
}

__global__ void bucket_scan_k(const int* __restrict__ bcount,
                              int* __restrict__ bbase, int* __restrict__ bcur, int K){
  __shared__ int v[128];
  const int t = threadIdx.x;     // 128 threads
  int orig = (t < K) ? bcount[t] : 0;
  v[t] = orig; __syncthreads();
  for (int off = 1; off < 128; off <<= 1){
    int y = (t >= off) ? v[t - off] : 0;
    __syncthreads();
    v[t] += y;
    __syncthreads();
  }
  int excl = v[t] - orig;
  if (t < K){ bbase[t] = excl; bcur[t] = excl; }
}

__global__ __launch_bounds__(256) void partition_k(const int* __restrict__ src,
                        const int* __restrict__ dst,
                        int* __restrict__ bcur, unsigned* __restrict__ packed, int E){
  __shared__ int lh[128];     // per-bucket local count, then local rank cursor
  __shared__ int lofs[128];   // global base reserved for this block
  const int t = threadIdx.x;
  for (int i = t; i < 128; i += TPB) lh[i] = 0;
  __syncthreads();
  const int c0 = blockIdx.x * EPB;
  int i1 = c0 + EPB; if (i1 > E) i1 = E;
  for (int i = c0 + t; i < i1; i += TPB)
    atomicAdd(&lh[dst[i] >> 9], 1);
  __syncthreads();
  if (t < 128){
    lofs[t] = lh[t] ? atomicAdd(&bcur[t], lh[t]) : 0;
    lh[t] = 0;
  }
  __syncthreads();
  for (int i = c0 + t; i < i1; i += TPB){
    int d = dst[i], k = d >> 9;
    int r = atomicAdd(&lh[k], 1);                       // LDS rank
    packed[lofs[k] + r] = ((unsigned)src[i] << 9) | (unsigned)(d & 511);
  }
}

// One block per bucket: LDS histogram + scan + scatter into the bucket's
// contiguous csr window; analytic global base (bbase[k] + k*BK self-loops).
__global__ __launch_bounds__(256) void bucket_csr_k(const unsigned* __restrict__ packed,
                        const int* __restrict__ bbase, const int* __restrict__ bcur,
                        int* __restrict__ row_off, int* __restrict__ csr_src,
                        int N, int E, int K){
  __shared__ int hist[BK];
  __shared__ int cur[BK];
  __shared__ int scan2[256];
  const int k = blockIdx.x;
  const int t = threadIdx.x;
  const int b0 = bbase[k], b1 = bcur[k];
  const int nb = k * BK;
  int nloc = N - nb; if (nloc > BK) nloc = BK;

  for (int i = t; i < BK; i += 256) hist[i] = 0;
  __syncthreads();
  for (int i = b0 + t; i < b1; i += 256)
    atomicAdd(&hist[packed[i] & 511u], 1);
  __syncthreads();

  int a0 = hist[2 * t], a1 = hist[2 * t + 1];
  int pair = a0 + a1;
  scan2[t] = pair; __syncthreads();
  for (int off = 1; off < 256; off <<= 1){
    int y = (t >= off) ? scan2[t - off] : 0;
    __syncthreads();
    scan2[t] += y;
    __syncthreads();
  }
  int pexcl = scan2[t] - pair;            // exclusive over pairs
  const int base = b0 + nb;               // global entry index of this bucket
  int i0 = 2 * t, i1n = 2 * t + 1;
  if (i0 < nloc){
    int r = base + pexcl + i0;
    row_off[nb + i0] = r;
    csr_src[r] = nb + i0;
    cur[i0] = r + 1;
  }
  if (i1n < nloc){
    int r = base + pexcl + a0 + i1n;
    row_off[nb + i1n] = r;
    csr_src[r] = nb + i1n;
    cur[i1n] = r + 1;
  }
  if (k == K - 1 && t == 0) row_off[N] = E + N;
  __syncthreads();

  for (int i = b0 + t; i < b1; i += 256){
    unsigned pk = packed[i];
    int p = atomicAdd(&cur[pk & 511u], 1);
    csr_src[p] = (int)(pk >> 9);
  }
}

// ---------------- fused single-pass softmax + aggregate + bias + relu ----------------
// one wave per node; fp8 payload, fp32 accumulate, bf16 act output.
// Edge table (sidx, weight) in per-wave LDS; gather loop 4x-unrolled so 4
// independent payload loads are in flight per iteration (latency hiding).
// Slots >= cnt carry t=0 -> branch-free; UNROLL*EPW divides 64 so slot<64.

template<int H, int C>
__global__ __launch_bounds__(256) void agg_k(const int* __restrict__ csr_src,
        const int* __restrict__ row_off,
        const float* __restrict__ es, const float* __restrict__ ed,
        const unsigned char* __restrict__ Hb, const float* __restrict__ b,
        ushort* __restrict__ outp, int N){
  constexpr int HC  = H * C;
  constexpr int LPE = HC / 8;         // lanes per edge
  constexpr int EPW = 64 / LPE;       // edges per wave-iteration
  constexpr int UN  = (EPW >= 32) ? (64 / EPW) : 4;   // gathers in flight
  __shared__ uint2 stg[4][64];
  const int lane = threadIdx.x & 63;
  const int wv   = threadIdx.x >> 6;
  const int n = blockIdx.x * 4 + wv;
  if (n >= N) return;
  const int beg = row_off[n];
  const int deg = row_off[n + 1] - beg;

  const int grp  = lane / LPE;        // which edge slot this lane serves
  const int cpos = lane % LPE;        // which 8-channel group
  const int c0   = cpos * 8;
  const int hd   = c0 / C;            // head of this lane's channels (8<=C)

  float edn[H];
#pragma unroll
  for (int h = 0; h < H; ++h) edn[h] = ed[n * H + h];

  float den[H];
#pragma unroll
  for (int h = 0; h < H; ++h) den[h] = 0.f;
  float acc[8] = {0.f,0.f,0.f,0.f,0.f,0.f,0.f,0.f};

  for (int base = 0; base < deg; base += 64){
    int j = base + lane;
    unsigned wbits = 0; int sidx = 0;
    if (j < deg){
      sidx = csr_src[beg + j];
      if (H == 2){
        float2 e2 = *(const float2*)(es + sidx * 2);
        float ea = e2.x + edn[0];
        ea = ea > 0.f ? ea : ea * NEG_SLOPE;
        ea = fminf(ea, 80.f);
        float ta = __expf(ea);
        float eb = e2.y + edn[1];
        eb = eb > 0.f ? eb : eb * NEG_SLOPE;
        eb = fminf(eb, 80.f);
        float tb = __expf(eb);
        den[0] += ta; den[1] += tb;
        wbits = pbf2(ta, tb);
      } else {
        float e = es[sidx] + edn[0];
        e = e > 0.f ? e : e * NEG_SLOPE;
        e = fminf(e, 80.f);
        float t0f = __expf(e);
        den[0] += t0f;
        wbits = __float_as_uint(t0f);
      }
    }
    // drain prior reads (WAR), publish this block's table, drain write (RAW)
    __asm__ volatile("s_waitcnt lgkmcnt(0)" ::: "memory");
    stg[wv][lane] = make_uint2((unsigned)sidx, wbits);
    __asm__ volatile("s_waitcnt lgkmcnt(0)" ::: "memory");

    int cnt = deg - base; if (cnt > 64) cnt = 64;
    for (int i = 0; i < cnt; i += UN * EPW){
      uint2 e[UN]; float tf[UN]; uint2 v[UN];
#pragma unroll
      for (int u = 0; u < UN; ++u) e[u] = stg[wv][i + u * EPW + grp];
#pragma unroll
      for (int u = 0; u < UN; ++u){
        if (H == 2) tf[u] = bf2f(hd ? (e[u].y >> 16) : (e[u].y & 0xffffu));
        else        tf[u] = __uint_as_float(e[u].y);
      }
#pragma unroll
      for (int u = 0; u < UN; ++u)
        v[u] = *(const uint2*)(Hb + (size_t)e[u].x * HC + c0);
#pragma unroll
      for (int u = 0; u < UN; ++u){
        v2f p0 = __builtin_amdgcn_cvt_pk_f32_fp8((int)v[u].x, false);
        v2f p1 = __builtin_amdgcn_cvt_pk_f32_fp8((int)v[u].x, true);
        v2f p2 = __builtin_amdgcn_cvt_pk_f32_fp8((int)v[u].y, false);
        v2f p3 = __builtin_amdgcn_cvt_pk_f32_fp8((int)v[u].y, true);
        acc[0] = fmaf(tf[u], p0[0], acc[0]); acc[1] = fmaf(tf[u], p0[1], acc[1]);
        acc[2] = fmaf(tf[u], p1[0], acc[2]); acc[3] = fmaf(tf[u], p1[1], acc[3]);
        acc[4] = fmaf(tf[u], p2[0], acc[4]); acc[5] = fmaf(tf[u], p2[1], acc[5]);
        acc[6] = fmaf(tf[u], p3[0], acc[6]); acc[7] = fmaf(tf[u], p3[1], acc[7]);
      }
    }
  }

  // reduce denominators across the wave
  float sinv[H];
#pragma unroll
  for (int h = 0; h < H; ++h){
    float v = den[h];
#pragma unroll
    for (int off = 32; off >= 1; off >>= 1) v += __shfl_xor(v, off);
    sinv[h] = 1.f / v;
  }

  // reduce partial channel sums across edge-slot groups
#pragma unroll
  for (int off = LPE; off < 64; off <<= 1){
#pragma unroll
    for (int k = 0; k < 8; ++k) acc[k] += __shfl_xor(acc[k], off);
  }

  if (grp == 0){
    float si = sinv[hd];
    float o[8];
#pragma unroll
    for (int k = 0; k < 8; ++k){
      float v = fmaf(acc[k], si, b[c0 + k]);
      o[k] = v > 0.f ? v : 0.f;
    }
    uint4 w;
    w.x = pbf2(o[0], o[1]); w.y = pbf2(o[2], o[3]);
    w.z = pbf2(o[4], o[5]); w.w = pbf2(o[6], o[7]);
    *(uint4*)(outp + (size_t)n * HC + c0) = w;
  }
}

// ---------------- pooling + FC ----------------

__global__ __launch_bounds__(256) void pool_k(const ushort* __restrict__ f,
                       const int* __restrict__ batch,
                       float* __restrict__ pooled, float* __restrict__ cnt, int N){
  __shared__ float sp[64 * 16];
  __shared__ float sc[64];
  const int t = threadIdx.x;
  for (int i = t; i < 64 * 16; i += 256) sp[i] = 0.f;
  for (int i = t; i < 64; i += 256) sc[i] = 0.f;
  __syncthreads();
  const int per = (N + gridDim.x - 1) / gridDim.x;
  const int n0 = blockIdx.x * per;
  int n1 = n0 + per; if (n1 > N) n1 = N;
  const int nloc = t >> 4, c = t & 15;
  for (int n = n0 + nloc; n < n1; n += 16){
    int g = batch[n];
    atomicAdd(&sp[g * 16 + c], bf2f(f[(size_t)n * 16 + c]));
    if (c == 0) atomicAdd(&sc[g], 1.f);
  }
  __syncthreads();
  for (int i = t; i < 64 * 16; i += 256) if (sp[i] != 0.f) atomicAdd(&pooled[i], sp[i]);
  for (int i = t; i < 64; i += 256)      if (sc[i] != 0.f) atomicAdd(&cnt[i], sc[i]);
}

__global__ void final_fc_k(const float* __restrict__ pooled, const float* __restrict__ cnt,
                           const float* __restrict__ fcW, const float* __restrict__ fcb,
                           float* __restrict__ outp){
  int g = threadIdx.x;
  if (g >= 64) return;
  float c = cnt[g]; c = c > 1.f ? c : 1.f;
  float inv = 1.0f / c;
  float acc = fcb[0];
  for (int i = 0; i < 16; ++i) acc = fmaf(pooled[g * 16 + i] * inv, fcW[i], acc);
  outp[g] = 1.0f / (1.0f + expf(-acc));
}

// ---------------- driver ----------------

extern "C" void kernel_launch(void* const* d_in, const int* in_sizes, int n_in,
                              void* d_out, int out_size, void* d_ws, size_t ws_size,
                              hipStream_t stream) {
  const float* x    = (const float*)d_in[0];
  const int*  ei    = (const int*)d_in[1];
  const int*  batch = (const int*)d_in[2];

  const int N = in_sizes[0] / 128;
  const int E = in_sizes[1] / 2;

  const int* src = ei;
  const int* dst = ei + E;

  const float* W_[5];  const float* as_[5]; const float* ad_[5]; const float* b_[5];
  for (int l = 0; l < 5; ++l) {
    W_[l]  = (const float*)d_in[3 + 4 * l + 0];
    as_[l] = (const float*)d_in[3 + 4 * l + 1];
    ad_[l] = (const float*)d_in[3 + 4 * l + 2];
    b_[l]  = (const float*)d_in[3 + 4 * l + 3];
  }
  const float* fcW = (const float*)d_in[23];
  const float* fcb = (const float*)d_in[24];
  float* outp = (float*)d_out;

  // workspace layout
  ushort*        f_buf  = (ushort*)d_ws;                      // N*128 bf16 activations
  unsigned char* Hb     = (unsigned char*)(f_buf + (size_t)N * 128); // N*128 fp8 payload
  float*         es     = (float*)(Hb + (size_t)N * 128);     // N*2
  float*         ed     = es + (size_t)N * 2;                 // N*2
  float*         pooled = ed + (size_t)N * 2;                 // 64*16
  float*         cnt    = pooled + 64 * 16;                   // 64
  int*           bcount = (int*)(cnt + 64);                   // 128
  int*           bbase  = bcount + 128;                       // 128
  int*           bcur   = bbase + 128;                        // 128
  int*           row_off= bcur + 128;                         // N+1
  int*           csr_src= row_off + N + 1;                    // E+N
  unsigned*      packed = (unsigned*)(csr_src + E + N);       // E

  const int K    = (N + BK - 1) / BK;                    // dst buckets
  const int nch  = cdiv_l(E, EPB);                       // edge chunks

  // ---- build CSR by destination (bucket-partitioned; reused by all 5 layers) ----
  hipMemsetAsync(bcount, 0, 128 * 4, stream);
  bucket_hist_k<<<nch, TPB, 0, stream>>>(dst, bcount, E);
  bucket_scan_k<<<1, 128, 0, stream>>>(bcount, bbase, bcur, K);
  partition_k<<<nch, TPB, 0, stream>>>(src, dst, bcur, packed, E);
  bucket_csr_k<<<K, 256, 0, stream>>>(packed, bbase, bcur, row_off, csr_src, N, E, K);

  const int gb = cdiv_l(N, 4);

  // layer 1: Fin=128, H=1, C=32 (fp32 input); NPB = 4096/HC
  gemm2_k<128,32,32,float><<<cdiv_l(N, 4096/32), 256, 0, stream>>>(x, W_[0], as_[0], ad_[0], es, ed, Hb, N);
  agg_k<1,32><<<gb, 256, 0, stream>>>(csr_src, row_off, es, ed, Hb, b_[0], f_buf, N);
  // layer 2: Fin=32, H=2, C=32
  gemm2_k<32,64,32,ushort><<<cdiv_l(N, 4096/64), 256, 0, stream>>>(f_buf, W_[1], as_[1], ad_[1], es, ed, Hb, N);
  agg_k<2,32><<<gb, 256, 0, stream>>>(csr_src, row_off, es, ed, Hb, b_[1], f_buf, N);
  // layer 3: Fin=64, H=2, C=64
  gemm2_k<64,128,64,ushort><<<cdiv_l(N, 4096/128), 256, 0, stream>>>(f_buf, W_[2], as_[2], ad_[2], es, ed, Hb, N);
  agg_k<2,64><<<gb, 256, 0, stream>>>(csr_src, row_off, es, ed, Hb, b_[2], f_buf, N);
  // layer 4: Fin=128, H=2, C=32
  gemm2_k<128,64,32,ushort><<<cdiv_l(N, 4096/64), 256, 0, stream>>>(f_buf, W_[3], as_[3], ad_[3], es, ed, Hb, N);
  agg_k<2,32><<<gb, 256, 0, stream>>>(csr_src, row_off, es, ed, Hb, b_[3], f_buf, N);
  // layer 5: Fin=64, H=2, C=8
  gemm2_k<64,16,8,ushort><<<cdiv_l(N, 4096/16), 256, 0, stream>>>(f_buf, W_[4], as_[4], ad_[4], es, ed, Hb, N);
  agg_k<2,8><<<gb, 256, 0, stream>>>(csr_src, row_off, es, ed, Hb, b_[4], f_buf, N);

  // global mean pool (G=64) + FC + sigmoid
  hipMemsetAsync(pooled, 0, (64 * 16 + 64) * 4, stream);
  pool_k<<<64, 256, 0, stream>>>(f_buf, batch, pooled, cnt, N);
  final_fc_k<<<1, 64, 0, stream>>>(pooled, cnt, fcW, fcb, outp);
}

// Round 18
// 313.347 us; speedup vs baseline: 1.1178x; 1.1178x over previous
//
#include <hip/hip_runtime.h>
#include <math.h>

#define TPB 256
#define NEG_SLOPE 0.2f
#define EPB 2048          // edges per block-chunk in streaming CSR kernels
#define BK 512            // nodes per bucket (dst>>9)

static inline int cdiv_l(long a, int b){ return (int)((a + b - 1) / b); }

typedef float v2f __attribute__((ext_vector_type(2)));
typedef short bf16x8 __attribute__((ext_vector_type(8)));
typedef float f32x4 __attribute__((ext_vector_type(4)));

__device__ __forceinline__ ushort f2bf(float f){
  unsigned u = __float_as_uint(f);
  unsigned r = u + 0x7fffu + ((u >> 16) & 1u);   // RNE
  return (ushort)(r >> 16);
}
__device__ __forceinline__ float bf2f(unsigned hi16){ return __uint_as_float(hi16 << 16); }
__device__ __forceinline__ unsigned pbf2(float a, float b){
  return (unsigned)f2bf(a) | ((unsigned)f2bf(b) << 16);
}

// ---------------- MFMA GEMM + fused attention dots + fp8 payload ----------------
// One wave = 16 nodes x HC channels. D[c][n] = sum_k W[k][c] X[n][k].
// A-frag: Wt[c][k] from LDS (row=lane&15 within ctile, k=8*(lane>>4)+j).
// B-frag: X[n][k] direct global 16B load (col=lane&15, k=8*(lane>>4)+j).
// C/D: col(n)=lane&15, row(c_local)=4*(lane>>4)+reg  [verified mapping].
template<int Fin, int HC, int C, typename XT>
__global__ __launch_bounds__(256) void gemm3_k(const XT* __restrict__ X,
        const float* __restrict__ W, const float* __restrict__ as_,
        const float* __restrict__ ad_, float* __restrict__ es, float* __restrict__ ed,
        unsigned char* __restrict__ Hb, int N){
  constexpr int H  = HC / C;
  constexpr int NC = HC / 16;          // channel tiles
  constexpr int KS = Fin / 32;         // k-steps
  __shared__ ushort Wt[HC][Fin + 4];   // W^T in bf16, padded row
  __shared__ float asl[HC], adl[HC];
  for (int idx = threadIdx.x; idx < Fin * HC; idx += 256){
    int k = idx / HC, c = idx - k * HC;
    Wt[c][k] = f2bf(W[idx]);
  }
  for (int i = threadIdx.x; i < HC; i += 256){ asl[i] = as_[i]; adl[i] = ad_[i]; }
  __syncthreads();

  const int lane = threadIdx.x & 63;
  const int wv   = threadIdx.x >> 6;
  const int n0 = (blockIdx.x * 4 + wv) * 16;
  if (n0 >= N) return;
  const int nl = lane & 15;            // node / A-row within tile
  const int kg = lane >> 4;            // k-group
  const int n  = n0 + nl;
  const bool valid = (n < N);
  const int nc = valid ? n : (N - 1);

  f32x4 acc[NC];
#pragma unroll
  for (int ct = 0; ct < NC; ++ct) acc[ct] = (f32x4){0.f, 0.f, 0.f, 0.f};

  for (int ks = 0; ks < KS; ++ks){
    const int k0 = ks * 32 + kg * 8;
    bf16x8 bfrag;
    if constexpr (sizeof(XT) == 2){
      bfrag = *(const bf16x8*)(X + (size_t)nc * Fin + k0);
    } else {
      float4 xa = *(const float4*)(X + (size_t)nc * Fin + k0);
      float4 xb = *(const float4*)(X + (size_t)nc * Fin + k0 + 4);
      bfrag[0] = (short)f2bf(xa.x); bfrag[1] = (short)f2bf(xa.y);
      bfrag[2] = (short)f2bf(xa.z); bfrag[3] = (short)f2bf(xa.w);
      bfrag[4] = (short)f2bf(xb.x); bfrag[5] = (short)f2bf(xb.y);
      bfrag[6] = (short)f2bf(xb.z); bfrag[7] = (short)f2bf(xb.w);
    }
#pragma unroll
    for (int ct = 0; ct < NC; ++ct){
      bf16x8 afrag = *(const bf16x8*)(&Wt[ct * 16 + nl][k0]);
      acc[ct] = __builtin_amdgcn_mfma_f32_16x16x32_bf16(afrag, bfrag, acc[ct], 0, 0, 0);
    }
  }

  // epilogue: fp8 payload + per-head attention dots
  float ps[H], pd[H];
#pragma unroll
  for (int h = 0; h < H; ++h){ ps[h] = 0.f; pd[h] = 0.f; }
#pragma unroll
  for (int ct = 0; ct < NC; ++ct){
    const int c0 = ct * 16 + kg * 4;
    int pk8 = __builtin_amdgcn_cvt_pk_fp8_f32(acc[ct][0], acc[ct][1], 0, false);
    pk8     = __builtin_amdgcn_cvt_pk_fp8_f32(acc[ct][2], acc[ct][3], pk8, true);
    if (valid) *(int*)(Hb + (size_t)n * HC + c0) = pk8;
    const int hd = c0 / C;             // 4 consecutive channels stay in one head (C>=8)
    float s = 0.f, d = 0.f;
#pragma unroll
    for (int j = 0; j < 4; ++j){
      s = fmaf(acc[ct][j], asl[c0 + j], s);
      d = fmaf(acc[ct][j], adl[c0 + j], d);
    }
    ps[hd] += s; pd[hd] += d;
  }
#pragma unroll
  for (int h = 0; h < H; ++h){
    ps[h] += __shfl_xor(ps[h], 16); ps[h] += __shfl_xor(ps[h], 32);
    pd[h] += __shfl_xor(pd[h], 16); pd[h] += __shfl_xor(pd[h], 32);
  }
  if (valid && lane < 16){
#pragma unroll
    for (int h = 0; h < H; ++h){
      es[n * H + h] = ps[h];
      ed[n * H + h] = pd[h];
    }
  }
}

// ---------------- CSR build: bucket partition + per-bucket counting sort ----------------

__global__ __launch_bounds__(256) void bucket_hist_k(const int* __restrict__ dst,
                        int* __restrict__ bcount, int E){
  __shared__ int lh[128];
  const int t = threadIdx.x;
  for (int i = t; i < 128; i += TPB) lh[i] = 0;
  __syncthreads();
  const int c0 = blockIdx.x * EPB;
  int i1 = c0 + EPB; if (i1 > E) i1 = E;
  for (int i = c0 + t; i < i1; i += TPB)
    atomicAdd(&lh[dst[i] >> 9], 1);
  __syncthreads();
  for (int i = t; i < 128; i += TPB)
    if (lh[i]) atomicAdd(&bcount[i], lh[i]);
}

__global__ void bucket_scan_k(const int* __restrict__ bcount,
                              int* __restrict__ bbase, int* __restrict__ bcur, int K){
  __shared__ int v[128];
  const int t = threadIdx.x;     // 128 threads
  int orig = (t < K) ? bcount[t] : 0;
  v[t] = orig; __syncthreads();
  for (int off = 1; off < 128; off <<= 1){
    int y = (t >= off) ? v[t - off] : 0;
    __syncthreads();
    v[t] += y;
    __syncthreads();
  }
  int excl = v[t] - orig;
  if (t < K){ bbase[t] = excl; bcur[t] = excl; }
}

__global__ __launch_bounds__(256) void partition_k(const int* __restrict__ src,
                        const int* __restrict__ dst,
                        int* __restrict__ bcur, unsigned* __restrict__ packed, int E){
  __shared__ int lh[128];     // per-bucket local count, then local rank cursor
  __shared__ int lofs[128];   // global base reserved for this block
  const int t = threadIdx.x;
  for (int i = t; i < 128; i += TPB) lh[i] = 0;
  __syncthreads();
  const int c0 = blockIdx.x * EPB;
  int i1 = c0 + EPB; if (i1 > E) i1 = E;
  for (int i = c0 + t; i < i1; i += TPB)
    atomicAdd(&lh[dst[i] >> 9], 1);
  __syncthreads();
  if (t < 128){
    lofs[t] = lh[t] ? atomicAdd(&bcur[t], lh[t]) : 0;
    lh[t] = 0;
  }
  __syncthreads();
  for (int i = c0 + t; i < i1; i += TPB){
    int d = dst[i], k = d >> 9;
    int r = atomicAdd(&lh[k], 1);                       // LDS rank
    packed[lofs[k] + r] = ((unsigned)src[i] << 9) | (unsigned)(d & 511);
  }
}

// One block per bucket: LDS histogram + scan + scatter into the bucket's
// contiguous csr window; analytic global base (bbase[k] + k*BK self-loops).
__global__ __launch_bounds__(256) void bucket_csr_k(const unsigned* __restrict__ packed,
                        const int* __restrict__ bbase, const int* __restrict__ bcur,
                        int* __restrict__ row_off, int* __restrict__ csr_src,
                        int N, int E, int K){
  __shared__ int hist[BK];
  __shared__ int cur[BK];
  __shared__ int scan2[256];
  const int k = blockIdx.x;
  const int t = threadIdx.x;
  const int b0 = bbase[k], b1 = bcur[k];
  const int nb = k * BK;
  int nloc = N - nb; if (nloc > BK) nloc = BK;

  for (int i = t; i < BK; i += 256) hist[i] = 0;
  __syncthreads();
  for (int i = b0 + t; i < b1; i += 256)
    atomicAdd(&hist[packed[i] & 511u], 1);
  __syncthreads();

  int a0 = hist[2 * t], a1 = hist[2 * t + 1];
  int pair = a0 + a1;
  scan2[t] = pair; __syncthreads();
  for (int off = 1; off < 256; off <<= 1){
    int y = (t >= off) ? scan2[t - off] : 0;
    __syncthreads();
    scan2[t] += y;
    __syncthreads();
  }
  int pexcl = scan2[t] - pair;            // exclusive over pairs
  const int base = b0 + nb;               // global entry index of this bucket
  int i0 = 2 * t, i1n = 2 * t + 1;
  if (i0 < nloc){
    int r = base + pexcl + i0;
    row_off[nb + i0] = r;
    csr_src[r] = nb + i0;
    cur[i0] = r + 1;
  }
  if (i1n < nloc){
    int r = base + pexcl + a0 + i1n;
    row_off[nb + i1n] = r;
    csr_src[r] = nb + i1n;
    cur[i1n] = r + 1;
  }
  if (k == K - 1 && t == 0) row_off[N] = E + N;
  __syncthreads();

  for (int i = b0 + t; i < b1; i += 256){
    unsigned pk = packed[i];
    int p = atomicAdd(&cur[pk & 511u], 1);
    csr_src[p] = (int)(pk >> 9);
  }
}

// ---------------- fused single-pass softmax + aggregate + bias + relu ----------------
// one wave per node; fp8 payload, fp32 accumulate, bf16 act output.
// Edge table (sidx, weight) in per-wave LDS; gather loop 4x-unrolled.

template<int H, int C>
__global__ __launch_bounds__(256) void agg_k(const int* __restrict__ csr_src,
        const int* __restrict__ row_off,
        const float* __restrict__ es, const float* __restrict__ ed,
        const unsigned char* __restrict__ Hb, const float* __restrict__ b,
        ushort* __restrict__ outp, int N){
  constexpr int HC  = H * C;
  constexpr int LPE = HC / 8;         // lanes per edge
  constexpr int EPW = 64 / LPE;       // edges per wave-iteration
  constexpr int UN  = (EPW >= 32) ? (64 / EPW) : 4;   // gathers in flight
  __shared__ uint2 stg[4][64];
  const int lane = threadIdx.x & 63;
  const int wv   = threadIdx.x >> 6;
  const int n = blockIdx.x * 4 + wv;
  if (n >= N) return;
  const int beg = row_off[n];
  const int deg = row_off[n + 1] - beg;

  const int grp  = lane / LPE;        // which edge slot this lane serves
  const int cpos = lane % LPE;        // which 8-channel group
  const int c0   = cpos * 8;
  const int hd   = c0 / C;            // head of this lane's channels (8<=C)

  float edn[H];
#pragma unroll
  for (int h = 0; h < H; ++h) edn[h] = ed[n * H + h];

  float den[H];
#pragma unroll
  for (int h = 0; h < H; ++h) den[h] = 0.f;
  float acc[8] = {0.f,0.f,0.f,0.f,0.f,0.f,0.f,0.f};

  for (int base = 0; base < deg; base += 64){
    int j = base + lane;
    unsigned wbits = 0; int sidx = 0;
    if (j < deg){
      sidx = csr_src[beg + j];
      if (H == 2){
        float2 e2 = *(const float2*)(es + sidx * 2);
        float ea = e2.x + edn[0];
        ea = ea > 0.f ? ea : ea * NEG_SLOPE;
        ea = fminf(ea, 80.f);
        float ta = __expf(ea);
        float eb = e2.y + edn[1];
        eb = eb > 0.f ? eb : eb * NEG_SLOPE;
        eb = fminf(eb, 80.f);
        float tb = __expf(eb);
        den[0] += ta; den[1] += tb;
        wbits = pbf2(ta, tb);
      } else {
        float e = es[sidx] + edn[0];
        e = e > 0.f ? e : e * NEG_SLOPE;
        e = fminf(e, 80.f);
        float t0f = __expf(e);
        den[0] += t0f;
        wbits = __float_as_uint(t0f);
      }
    }
    // drain prior reads (WAR), publish this block's table, drain write (RAW)
    __asm__ volatile("s_waitcnt lgkmcnt(0)" ::: "memory");
    stg[wv][lane] = make_uint2((unsigned)sidx, wbits);
    __asm__ volatile("s_waitcnt lgkmcnt(0)" ::: "memory");

    int cnt = deg - base; if (cnt > 64) cnt = 64;
    for (int i = 0; i < cnt; i += UN * EPW){
      uint2 e[UN]; float tf[UN]; uint2 v[UN];
#pragma unroll
      for (int u = 0; u < UN; ++u) e[u] = stg[wv][i + u * EPW + grp];
#pragma unroll
      for (int u = 0; u < UN; ++u){
        if (H == 2) tf[u] = bf2f(hd ? (e[u].y >> 16) : (e[u].y & 0xffffu));
        else        tf[u] = __uint_as_float(e[u].y);
      }
#pragma unroll
      for (int u = 0; u < UN; ++u)
        v[u] = *(const uint2*)(Hb + (size_t)e[u].x * HC + c0);
#pragma unroll
      for (int u = 0; u < UN; ++u){
        v2f p0 = __builtin_amdgcn_cvt_pk_f32_fp8((int)v[u].x, false);
        v2f p1 = __builtin_amdgcn_cvt_pk_f32_fp8((int)v[u].x, true);
        v2f p2 = __builtin_amdgcn_cvt_pk_f32_fp8((int)v[u].y, false);
        v2f p3 = __builtin_amdgcn_cvt_pk_f32_fp8((int)v[u].y, true);
        acc[0] = fmaf(tf[u], p0[0], acc[0]); acc[1] = fmaf(tf[u], p0[1], acc[1]);
        acc[2] = fmaf(tf[u], p1[0], acc[2]); acc[3] = fmaf(tf[u], p1[1], acc[3]);
        acc[4] = fmaf(tf[u], p2[0], acc[4]); acc[5] = fmaf(tf[u], p2[1], acc[5]);
        acc[6] = fmaf(tf[u], p3[0], acc[6]); acc[7] = fmaf(tf[u], p3[1], acc[7]);
      }
    }
  }

  // reduce denominators across the wave
  float sinv[H];
#pragma unroll
  for (int h = 0; h < H; ++h){
    float v = den[h];
#pragma unroll
    for (int off = 32; off >= 1; off >>= 1) v += __shfl_xor(v, off);
    sinv[h] = 1.f / v;
  }

  // reduce partial channel sums across edge-slot groups
#pragma unroll
  for (int off = LPE; off < 64; off <<= 1){
#pragma unroll
    for (int k = 0; k < 8; ++k) acc[k] += __shfl_xor(acc[k], off);
  }

  if (grp == 0){
    float si = sinv[hd];
    float o[8];
#pragma unroll
    for (int k = 0; k < 8; ++k){
      float v = fmaf(acc[k], si, b[c0 + k]);
      o[k] = v > 0.f ? v : 0.f;
    }
    uint4 w;
    w.x = pbf2(o[0], o[1]); w.y = pbf2(o[2], o[3]);
    w.z = pbf2(o[4], o[5]); w.w = pbf2(o[6], o[7]);
    *(uint4*)(outp + (size_t)n * HC + c0) = w;
  }
}

// ---------------- pooling + FC ----------------

__global__ __launch_bounds__(256) void pool_k(const ushort* __restrict__ f,
                       const int* __restrict__ batch,
                       float* __restrict__ pooled, float* __restrict__ cnt, int N){
  __shared__ float sp[64 * 16];
  __shared__ float sc[64];
  const int t = threadIdx.x;
  for (int i = t; i < 64 * 16; i += 256) sp[i] = 0.f;
  for (int i = t; i < 64; i += 256) sc[i] = 0.f;
  __syncthreads();
  const int per = (N + gridDim.x - 1) / gridDim.x;
  const int n0 = blockIdx.x * per;
  int n1 = n0 + per; if (n1 > N) n1 = N;
  const int nloc = t >> 4, c = t & 15;
  for (int n = n0 + nloc; n < n1; n += 16){
    int g = batch[n];
    atomicAdd(&sp[g * 16 + c], bf2f(f[(size_t)n * 16 + c]));
    if (c == 0) atomicAdd(&sc[g], 1.f);
  }
  __syncthreads();
  for (int i = t; i < 64 * 16; i += 256) if (sp[i] != 0.f) atomicAdd(&pooled[i], sp[i]);
  for (int i = t; i < 64; i += 256)      if (sc[i] != 0.f) atomicAdd(&cnt[i], sc[i]);
}

__global__ void final_fc_k(const float* __restrict__ pooled, const float* __restrict__ cnt,
                           const float* __restrict__ fcW, const float* __restrict__ fcb,
                           float* __restrict__ outp){
  int g = threadIdx.x;
  if (g >= 64) return;
  float c = cnt[g]; c = c > 1.f ? c : 1.f;
  float inv = 1.0f / c;
  float acc = fcb[0];
  for (int i = 0; i < 16; ++i) acc = fmaf(pooled[g * 16 + i] * inv, fcW[i], acc);
  outp[g] = 1.0f / (1.0f + expf(-acc));
}

// ---------------- driver ----------------

extern "C" void kernel_launch(void* const* d_in, const int* in_sizes, int n_in,
                              void* d_out, int out_size, void* d_ws, size_t ws_size,
                              hipStream_t stream) {
  const float* x    = (const float*)d_in[0];
  const int*  ei    = (const int*)d_in[1];
  const int*  batch = (const int*)d_in[2];

  const int N = in_sizes[0] / 128;
  const int E = in_sizes[1] / 2;

  const int* src = ei;
  const int* dst = ei + E;

  const float* W_[5];  const float* as_[5]; const float* ad_[5]; const float* b_[5];
  for (int l = 0; l < 5; ++l) {
    W_[l]  = (const float*)d_in[3 + 4 * l + 0];
    as_[l] = (const float*)d_in[3 + 4 * l + 1];
    ad_[l] = (const float*)d_in[3 + 4 * l + 2];
    b_[l]  = (const float*)d_in[3 + 4 * l + 3];
  }
  const float* fcW = (const float*)d_in[23];
  const float* fcb = (const float*)d_in[24];
  float* outp = (float*)d_out;

  // workspace layout
  ushort*        f_buf  = (ushort*)d_ws;                      // N*128 bf16 activations
  unsigned char* Hb     = (unsigned char*)(f_buf + (size_t)N * 128); // N*128 fp8 payload
  float*         es     = (float*)(Hb + (size_t)N * 128);     // N*2
  float*         ed     = es + (size_t)N * 2;                 // N*2
  float*         pooled = ed + (size_t)N * 2;                 // 64*16
  float*         cnt    = pooled + 64 * 16;                   // 64
  int*           bcount = (int*)(cnt + 64);                   // 128
  int*           bbase  = bcount + 128;                       // 128
  int*           bcur   = bbase + 128;                        // 128
  int*           row_off= bcur + 128;                         // N+1
  int*           csr_src= row_off + N + 1;                    // E+N
  unsigned*      packed = (unsigned*)(csr_src + E + N);       // E

  const int K    = (N + BK - 1) / BK;                    // dst buckets
  const int nch  = cdiv_l(E, EPB);                       // edge chunks

  // ---- build CSR by destination (bucket-partitioned; reused by all 5 layers) ----
  hipMemsetAsync(bcount, 0, 128 * 4, stream);
  bucket_hist_k<<<nch, TPB, 0, stream>>>(dst, bcount, E);
  bucket_scan_k<<<1, 128, 0, stream>>>(bcount, bbase, bcur, K);
  partition_k<<<nch, TPB, 0, stream>>>(src, dst, bcur, packed, E);
  bucket_csr_k<<<K, 256, 0, stream>>>(packed, bbase, bcur, row_off, csr_src, N, E, K);

  const int gb = cdiv_l(N, 4);
  const int gg = cdiv_l(N, 64);   // gemm3: 4 waves x 16 nodes per block

  // layer 1: Fin=128, H=1, C=32 (fp32 input)
  gemm3_k<128,32,32,float><<<gg, 256, 0, stream>>>(x, W_[0], as_[0], ad_[0], es, ed, Hb, N);
  agg_k<1,32><<<gb, 256, 0, stream>>>(csr_src, row_off, es, ed, Hb, b_[0], f_buf, N);
  // layer 2: Fin=32, H=2, C=32
  gemm3_k<32,64,32,ushort><<<gg, 256, 0, stream>>>(f_buf, W_[1], as_[1], ad_[1], es, ed, Hb, N);
  agg_k<2,32><<<gb, 256, 0, stream>>>(csr_src, row_off, es, ed, Hb, b_[1], f_buf, N);
  // layer 3: Fin=64, H=2, C=64
  gemm3_k<64,128,64,ushort><<<gg, 256, 0, stream>>>(f_buf, W_[2], as_[2], ad_[2], es, ed, Hb, N);
  agg_k<2,64><<<gb, 256, 0, stream>>>(csr_src, row_off, es, ed, Hb, b_[2], f_buf, N);
  // layer 4: Fin=128, H=2, C=32
  gemm3_k<128,64,32,ushort><<<gg, 256, 0, stream>>>(f_buf, W_[3], as_[3], ad_[3], es, ed, Hb, N);
  agg_k<2,32><<<gb, 256, 0, stream>>>(csr_src, row_off, es, ed, Hb, b_[3], f_buf, N);
  // layer 5: Fin=64, H=2, C=8
  gemm3_k<64,16,8,ushort><<<gg, 256, 0, stream>>>(f_buf, W_[4], as_[4], ad_[4], es, ed, Hb, N);
  agg_k<2,8><<<gb, 256, 0, stream>>>(csr_src, row_off, es, ed, Hb, b_[4], f_buf, N);

  // global mean pool (G=64) + FC + sigmoid
  hipMemsetAsync(pooled, 0, (64 * 16 + 64) * 4, stream);
  pool_k<<<64, 256, 0, stream>>>(f_buf, batch, pooled, cnt, N);
  final_fc_k<<<1, 64, 0, stream>>>(pooled, cnt, fcW, fcb, outp);
}